// Round 2
// baseline (196.727 us; speedup 1.0000x reference)
//
#include <hip/hip_runtime.h>

// CoPE: gated reverse-cumsum positions + interpolated positional logits.
// B=2,H=16,S=2048,D=64,NPOS=64 -> 65536 rows of length 2048.
//
// Two-kernel split:
//   A (scan): per row, compute logits_int (64-wide shuffle einsum), backward
//     early-exit suffix-scan of sigmoid(attn) in 64-wide chunks, write the
//     ~128-col scan region, and record {jb, l63} in d_ws.
//     Once carry >= 63, pos clamps to 63 -> w == 0 -> out == logits_int[63]
//     for ALL earlier columns.
//   B (fill): pure store kernel, fills [0, jb) with l63 — same structure as
//     the harness's fillBufferAligned which measures 6.5 TB/s on this chip.
// Rationale: R1 monolithic kernel hit only 3.65 TB/s because each wave's
// latency-bound prologue (serial HBM chunk loads + DS-pipe scan) starved the
// store pipe. 94% of bytes are the constant fill -> give them a pure kernel.

#define SLEN 2048
#define DDIM 64
#define NPOSN 64
#define ROWS (2 * 16 * 2048)

__global__ __launch_bounds__(256) void cope_scan_kernel(
    const float* __restrict__ q,     // [65536, 64]
    const float* __restrict__ attn,  // [65536, 2048]
    const float* __restrict__ emb,   // [64, 64]
    float* __restrict__ out,         // [65536, 2048]
    int*   __restrict__ jb_ws,       // [65536]
    float* __restrict__ l63_ws)      // [65536]
{
    const int lane = threadIdx.x & 63;
    const int wave = threadIdx.x >> 6;
    const int r = blockIdx.x * 4 + wave;

    // logits_int[lane] = sum_d q[r][d] * emb[d][lane]  (2 chains for ILP)
    const float qv = q[(size_t)r * DDIM + lane];
    float lv0 = 0.0f, lv1 = 0.0f;
    #pragma unroll
    for (int d = 0; d < DDIM; d += 2) {
        lv0 = fmaf(__shfl(qv, d),     emb[d * NPOSN + lane],       lv0);
        lv1 = fmaf(__shfl(qv, d + 1), emb[(d + 1) * NPOSN + lane], lv1);
    }
    const float lv  = lv0 + lv1;
    const float l63 = __shfl(lv, NPOSN - 1);

    const float* __restrict__ arow = attn + (size_t)r * SLEN;
    float* __restrict__ orow = out + (size_t)r * SLEN;

    // backward chunked scan, software-pipelined load, early exit
    float carry = 0.0f;
    int jb = SLEN;
    float x = arow[SLEN - 64 + lane];
    for (;;) {
        jb -= 64;
        float xn = 0.0f;
        if (jb > 0) xn = arow[jb - 64 + lane];   // prefetch next chunk
        const float g = 1.0f / (1.0f + __expf(-x));
        float s = g;                              // reverse inclusive scan
        #pragma unroll
        for (int off = 1; off < 64; off <<= 1) {
            const float t = __shfl_down(s, off);
            if (lane + off < 64) s += t;
        }
        const float pos = fminf(carry + s, 63.0f);
        const float pf  = floorf(pos);
        const float w   = pos - pf;
        const float lf  = __shfl(lv, (int)pf);
        const float lc  = __shfl(lv, (int)ceilf(pos));
        orow[jb + lane] = lc * w + lf * (1.0f - w);
        carry += __shfl(s, 0);
        if (carry >= 63.0f || jb == 0) break;
        x = xn;
    }
    if (lane == 0) {
        jb_ws[r]  = jb;
        l63_ws[r] = l63;
    }
}

__global__ __launch_bounds__(256) void cope_fill_kernel(
    const int*   __restrict__ jb_ws,
    const float* __restrict__ l63_ws,
    float* __restrict__ out)
{
    const int lane = threadIdx.x & 63;
    const int wave = threadIdx.x >> 6;
    const int r = blockIdx.x * 4 + wave;
    const int jb = jb_ws[r];            // multiple of 64
    const float l63 = l63_ws[r];
    float* __restrict__ orow = out + (size_t)r * SLEN;
    const float4 v4 = make_float4(l63, l63, l63, l63);
    for (int j = lane * 4; j < jb; j += 256) {
        *reinterpret_cast<float4*>(orow + j) = v4;
    }
}

// R1 monolithic fallback (used only if ws_size is too small)
__global__ __launch_bounds__(256) void cope_mono_kernel(
    const float* __restrict__ q, const float* __restrict__ attn,
    const float* __restrict__ emb, float* __restrict__ out)
{
    const int lane = threadIdx.x & 63;
    const int wave = threadIdx.x >> 6;
    const int r = blockIdx.x * 4 + wave;
    const float qv = q[(size_t)r * DDIM + lane];
    float lv = 0.0f;
    #pragma unroll
    for (int d = 0; d < DDIM; ++d)
        lv = fmaf(__shfl(qv, d), emb[d * NPOSN + lane], lv);
    const float l63 = __shfl(lv, NPOSN - 1);
    const float* __restrict__ arow = attn + (size_t)r * SLEN;
    float* __restrict__ orow = out + (size_t)r * SLEN;
    float carry = 0.0f;
    int jb = SLEN;
    while (jb > 0) {
        jb -= 64;
        const float x = arow[jb + lane];
        const float g = 1.0f / (1.0f + __expf(-x));
        float s = g;
        #pragma unroll
        for (int off = 1; off < 64; off <<= 1) {
            const float t = __shfl_down(s, off);
            if (lane + off < 64) s += t;
        }
        const float pos = fminf(carry + s, 63.0f);
        const float pf  = floorf(pos);
        const float w   = pos - pf;
        const float lf  = __shfl(lv, (int)pf);
        const float lc  = __shfl(lv, (int)ceilf(pos));
        orow[jb + lane] = lc * w + lf * (1.0f - w);
        carry += __shfl(s, 0);
        if (carry >= 63.0f) break;
    }
    const float4 v4 = make_float4(l63, l63, l63, l63);
    for (int j = lane * 4; j < jb; j += 256)
        *reinterpret_cast<float4*>(orow + j) = v4;
}

extern "C" void kernel_launch(void* const* d_in, const int* in_sizes, int n_in,
                              void* d_out, int out_size, void* d_ws, size_t ws_size,
                              hipStream_t stream) {
    const float* q    = (const float*)d_in[0];
    const float* attn = (const float*)d_in[1];
    const float* emb  = (const float*)d_in[2];
    float* out = (float*)d_out;

    const size_t ws_need = (size_t)ROWS * (sizeof(int) + sizeof(float));
    dim3 grid(ROWS / 4), block(256);
    if (ws_size >= ws_need && d_ws != nullptr) {
        int*   jb_ws  = (int*)d_ws;
        float* l63_ws = (float*)((char*)d_ws + (size_t)ROWS * sizeof(int));
        cope_scan_kernel<<<grid, block, 0, stream>>>(q, attn, emb, out, jb_ws, l63_ws);
        cope_fill_kernel<<<grid, block, 0, stream>>>(jb_ws, l63_ws, out);
    } else {
        cope_mono_kernel<<<grid, block, 0, stream>>>(q, attn, emb, out);
    }
}

// Round 3
// 172.126 us; speedup vs baseline: 1.1429x; 1.1429x over previous
//
#include <hip/hip_runtime.h>

// CoPE: gated reverse-cumsum positions + interpolated positional logits.
// B=2,H=16,S=2048,D=64,NPOS=64 -> 65536 rows of length 2048.
//
// R2 lesson: the global A->B split serialized scan vs fill and exposed that
// the per-row einsum (64 VMEM + 64 shfl + 64 FMA = ~200 instrs/row) is the
// dominant non-store cost. R3 structure:
//   T (table): GEMM-style kernel, lane=row, 64 rows/wave, q in 64 VGPRs,
//     emb via wave-uniform scalar loads -> logits_int table [65536][64] in ws.
//     No shuffles. ~4096 FMA/wave, 16 MB write. ~5-10 us.
//   M (main): monolithic per-row scan+fill (keeps scan||fill overlap across
//     waves). Row table = ONE coalesced 256B load (L3-resident). Then
//     backward early-exit suffix scan + constant fill, as R1.

#define SLEN 2048
#define DDIM 64
#define NPOSN 64
#define ROWS (2 * 16 * 2048)

// ---- kernel T: logits_int[r][n] = sum_d q[r][d] * emb[d][n] ----
// grid 256 x 256thr; wave handles 64 consecutive rows, lane = row.
__global__ __launch_bounds__(256) void cope_table_kernel(
    const float* __restrict__ q,      // [65536, 64]
    const float* __restrict__ emb,    // [64, 64]
    float* __restrict__ table)        // [65536, 64]
{
    const int lane = threadIdx.x & 63;
    const int wave = threadIdx.x >> 6;
    const int r = (blockIdx.x * 4 + wave) * 64 + lane;   // this lane's row

    // q[r][0..63] into registers (static-indexed after unroll)
    float qr[DDIM];
    const float4* __restrict__ q4 = (const float4*)(q + (size_t)r * DDIM);
    #pragma unroll
    for (int i = 0; i < DDIM / 4; ++i) {
        const float4 t = q4[i];
        qr[4 * i + 0] = t.x; qr[4 * i + 1] = t.y;
        qr[4 * i + 2] = t.z; qr[4 * i + 3] = t.w;
    }

    float* __restrict__ trow = table + (size_t)r * NPOSN;
    // two halves of 32 cols to keep VGPR pressure moderate
    #pragma unroll
    for (int h = 0; h < 2; ++h) {
        float acc[32];
        #pragma unroll
        for (int n = 0; n < 32; ++n) acc[n] = 0.0f;
        #pragma unroll
        for (int d = 0; d < DDIM; ++d) {
            const float qd = qr[d];
            const float* __restrict__ erow = emb + d * NPOSN + h * 32;
            #pragma unroll
            for (int n = 0; n < 32; ++n)
                acc[n] = fmaf(qd, erow[n], acc[n]);   // erow[n] wave-uniform -> s_load
        }
        float4* __restrict__ t4 = (float4*)(trow + h * 32);
        #pragma unroll
        for (int n = 0; n < 8; ++n)
            t4[n] = make_float4(acc[4 * n], acc[4 * n + 1],
                                acc[4 * n + 2], acc[4 * n + 3]);
    }
}

// ---- kernel M: per-row backward early-exit scan + constant fill ----
__global__ __launch_bounds__(256) void cope_main_kernel(
    const float* __restrict__ attn,   // [65536, 2048]
    const float* __restrict__ table,  // [65536, 64]
    float* __restrict__ out)          // [65536, 2048]
{
    const int lane = threadIdx.x & 63;
    const int wave = threadIdx.x >> 6;
    const int r = blockIdx.x * 4 + wave;

    const float lv  = table[(size_t)r * NPOSN + lane];  // coalesced 256B
    const float l63 = __shfl(lv, NPOSN - 1);

    const float* __restrict__ arow = attn + (size_t)r * SLEN;
    float* __restrict__ orow = out + (size_t)r * SLEN;

    float carry = 0.0f;
    int jb = SLEN;
    float x = arow[SLEN - 64 + lane];
    for (;;) {
        jb -= 64;
        float xn = 0.0f;
        if (jb > 0) xn = arow[jb - 64 + lane];          // prefetch next chunk
        const float g = 1.0f / (1.0f + __expf(-x));     // sigmoid
        float s = g;                                     // reverse incl. scan
        #pragma unroll
        for (int off = 1; off < 64; off <<= 1) {
            const float t = __shfl_down(s, off);
            if (lane + off < 64) s += t;
        }
        const float pos = fminf(carry + s, 63.0f);
        const float pf  = floorf(pos);
        const float w   = pos - pf;
        const float lf  = __shfl(lv, (int)pf);
        const float lc  = __shfl(lv, (int)ceilf(pos));
        orow[jb + lane] = lc * w + lf * (1.0f - w);
        carry += __shfl(s, 0);
        if (carry >= 63.0f || jb == 0) break;
        x = xn;
    }

    const float4 v4 = make_float4(l63, l63, l63, l63);
    for (int j = lane * 4; j < jb; j += 256)
        *reinterpret_cast<float4*>(orow + j) = v4;
}

// ---- fallback: R1 monolithic (if ws too small for the 16 MB table) ----
__global__ __launch_bounds__(256) void cope_mono_kernel(
    const float* __restrict__ q, const float* __restrict__ attn,
    const float* __restrict__ emb, float* __restrict__ out)
{
    const int lane = threadIdx.x & 63;
    const int wave = threadIdx.x >> 6;
    const int r = blockIdx.x * 4 + wave;
    const float qv = q[(size_t)r * DDIM + lane];
    float lv = 0.0f;
    #pragma unroll
    for (int d = 0; d < DDIM; ++d)
        lv = fmaf(__shfl(qv, d), emb[d * NPOSN + lane], lv);
    const float l63 = __shfl(lv, NPOSN - 1);
    const float* __restrict__ arow = attn + (size_t)r * SLEN;
    float* __restrict__ orow = out + (size_t)r * SLEN;
    float carry = 0.0f;
    int jb = SLEN;
    while (jb > 0) {
        jb -= 64;
        const float x = arow[jb + lane];
        const float g = 1.0f / (1.0f + __expf(-x));
        float s = g;
        #pragma unroll
        for (int off = 1; off < 64; off <<= 1) {
            const float t = __shfl_down(s, off);
            if (lane + off < 64) s += t;
        }
        const float pos = fminf(carry + s, 63.0f);
        const float pf  = floorf(pos);
        const float w   = pos - pf;
        const float lf  = __shfl(lv, (int)pf);
        const float lc  = __shfl(lv, (int)ceilf(pos));
        orow[jb + lane] = lc * w + lf * (1.0f - w);
        carry += __shfl(s, 0);
        if (carry >= 63.0f) break;
    }
    const float4 v4 = make_float4(l63, l63, l63, l63);
    for (int j = lane * 4; j < jb; j += 256)
        *reinterpret_cast<float4*>(orow + j) = v4;
}

extern "C" void kernel_launch(void* const* d_in, const int* in_sizes, int n_in,
                              void* d_out, int out_size, void* d_ws, size_t ws_size,
                              hipStream_t stream) {
    const float* q    = (const float*)d_in[0];
    const float* attn = (const float*)d_in[1];
    const float* emb  = (const float*)d_in[2];
    float* out = (float*)d_out;

    const size_t ws_need = (size_t)ROWS * NPOSN * sizeof(float);   // 16 MB
    dim3 block(256);
    if (ws_size >= ws_need && d_ws != nullptr) {
        float* table = (float*)d_ws;
        cope_table_kernel<<<dim3(ROWS / 64 / 4), block, 0, stream>>>(q, emb, table);
        cope_main_kernel<<<dim3(ROWS / 4), block, 0, stream>>>(attn, table, out);
    } else {
        cope_mono_kernel<<<dim3(ROWS / 4), block, 0, stream>>>(q, attn, emb, out);
    }
}

// Round 4
// 171.274 us; speedup vs baseline: 1.1486x; 1.0050x over previous
//
#include <hip/hip_runtime.h>

// CoPE: gated reverse-cumsum positions + interpolated positional logits.
// B=2,H=16,S=2048,D=64,NPOS=64 -> 65536 rows of length 2048.
//
// R3 lesson: scan kernel is latency-bound, not instruction-bound. Each
// 1-row wave serializes {HBM chunk-load latency + 6-deep bpermute scan}
// before issuing any store -> store pipe starves (~3.7 TB/s vs 6.5 fill).
// R4: 4 rows/wave. Issue all 12 chunk loads + 4 table loads upfront
// (latencies overlap); per row scan the 3 chunks' independent chains in
// ONE 6-step shuffle loop (depth 6 DS ops, not 18); stores of row i
// overlap scan of row i+1. Suffix sum over 192 gates ~ 96 >> 63, so 3
// chunks always complete the unclamped region (demand-load slow path
// retained for correctness).

#define SLEN 2048
#define DDIM 64
#define NPOSN 64
#define ROWS (2 * 16 * 2048)
#define RPW 4            // rows per wave

__device__ __forceinline__ float sigmoidf_(float x) {
    return 1.0f / (1.0f + __expf(-x));
}

// ---- kernel T: logits_int[r][n] = sum_d q[r][d] * emb[d][n] ----
__global__ __launch_bounds__(256) void cope_table_kernel(
    const float* __restrict__ q,      // [65536, 64]
    const float* __restrict__ emb,    // [64, 64]
    float* __restrict__ table)        // [65536, 64]
{
    const int lane = threadIdx.x & 63;
    const int wave = threadIdx.x >> 6;
    const int r = (blockIdx.x * 4 + wave) * 64 + lane;   // lane = row

    float qr[DDIM];
    const float4* __restrict__ q4 = (const float4*)(q + (size_t)r * DDIM);
    #pragma unroll
    for (int i = 0; i < DDIM / 4; ++i) {
        const float4 t = q4[i];
        qr[4 * i + 0] = t.x; qr[4 * i + 1] = t.y;
        qr[4 * i + 2] = t.z; qr[4 * i + 3] = t.w;
    }
    float* __restrict__ trow = table + (size_t)r * NPOSN;
    #pragma unroll
    for (int h = 0; h < 2; ++h) {
        float acc[32];
        #pragma unroll
        for (int n = 0; n < 32; ++n) acc[n] = 0.0f;
        #pragma unroll
        for (int d = 0; d < DDIM; ++d) {
            const float qd = qr[d];
            const float* __restrict__ erow = emb + d * NPOSN + h * 32;
            #pragma unroll
            for (int n = 0; n < 32; ++n)
                acc[n] = fmaf(qd, erow[n], acc[n]);   // wave-uniform -> s_load
        }
        float4* __restrict__ t4 = (float4*)(trow + h * 32);
        #pragma unroll
        for (int n = 0; n < 8; ++n)
            t4[n] = make_float4(acc[4 * n], acc[4 * n + 1],
                                acc[4 * n + 2], acc[4 * n + 3]);
    }
}

// ---- kernel M: 4 rows/wave, batched prefetch, parallel 3-chunk scan ----
__global__ __launch_bounds__(256) void cope_main_kernel(
    const float* __restrict__ attn,   // [65536, 2048]
    const float* __restrict__ table,  // [65536, 64]
    float* __restrict__ out)          // [65536, 2048]
{
    const int lane = threadIdx.x & 63;
    const int wave = threadIdx.x >> 6;
    const int r0 = (blockIdx.x * 4 + wave) * RPW;

    // upfront: all chunk loads (3 per row) + table rows -> latencies overlap
    float c[RPW][3];
    float lv[RPW];
    #pragma unroll
    for (int i = 0; i < RPW; ++i) {
        const float* __restrict__ arow = attn + (size_t)(r0 + i) * SLEN;
        c[i][0] = arow[SLEN -  64 + lane];
        c[i][1] = arow[SLEN - 128 + lane];
        c[i][2] = arow[SLEN - 192 + lane];
        lv[i]   = table[(size_t)(r0 + i) * NPOSN + lane];
    }

    #pragma unroll
    for (int i = 0; i < RPW; ++i) {
        const float lvi = lv[i];
        float* __restrict__ orow = out + (size_t)(r0 + i) * SLEN;

        // three independent reverse inclusive scans, one 6-step loop
        float s0 = sigmoidf_(c[i][0]);
        float s1 = sigmoidf_(c[i][1]);
        float s2 = sigmoidf_(c[i][2]);
        #pragma unroll
        for (int off = 1; off < 64; off <<= 1) {
            const float t0 = __shfl_down(s0, off);
            const float t1 = __shfl_down(s1, off);
            const float t2 = __shfl_down(s2, off);
            if (lane + off < 64) { s0 += t0; s1 += t1; s2 += t2; }
        }
        const float T0 = __shfl(s0, 0);
        const float T1 = __shfl(s1, 0);
        const float T2 = __shfl(s2, 0);

        // interpolate + store the three scanned chunks
        {
            const float pos = fminf(s0, 63.0f);
            const float pf = floorf(pos), w = pos - pf;
            const float lf = __shfl(lvi, (int)pf);
            const float lc = __shfl(lvi, (int)ceilf(pos));
            orow[SLEN - 64 + lane] = lc * w + lf * (1.0f - w);
        }
        {
            const float pos = fminf(T0 + s1, 63.0f);
            const float pf = floorf(pos), w = pos - pf;
            const float lf = __shfl(lvi, (int)pf);
            const float lc = __shfl(lvi, (int)ceilf(pos));
            orow[SLEN - 128 + lane] = lc * w + lf * (1.0f - w);
        }
        {
            const float pos = fminf(T0 + T1 + s2, 63.0f);
            const float pf = floorf(pos), w = pos - pf;
            const float lf = __shfl(lvi, (int)pf);
            const float lc = __shfl(lvi, (int)ceilf(pos));
            orow[SLEN - 192 + lane] = lc * w + lf * (1.0f - w);
        }

        float carry = T0 + T1 + T2;
        int jb = SLEN - 192;

        // slow path (P ~ 0 for this data, required for correctness)
        const float* __restrict__ arow = attn + (size_t)(r0 + i) * SLEN;
        while (carry < 63.0f && jb > 0) {
            jb -= 64;
            const float x = arow[jb + lane];
            float s = sigmoidf_(x);
            #pragma unroll
            for (int off = 1; off < 64; off <<= 1) {
                const float t = __shfl_down(s, off);
                if (lane + off < 64) s += t;
            }
            const float pos = fminf(carry + s, 63.0f);
            const float pf = floorf(pos), w = pos - pf;
            const float lf = __shfl(lvi, (int)pf);
            const float lc = __shfl(lvi, (int)ceilf(pos));
            orow[jb + lane] = lc * w + lf * (1.0f - w);
            carry += __shfl(s, 0);
        }

        // fill [0, jb) with logits_int[63] (pos clamps -> w == 0)
        const float l63 = __shfl(lvi, NPOSN - 1);
        const float4 v4 = make_float4(l63, l63, l63, l63);
        for (int j = lane * 4; j < jb; j += 256)
            *reinterpret_cast<float4*>(orow + j) = v4;
    }
}

// ---- fallback: monolithic (if ws too small for the 16 MB table) ----
__global__ __launch_bounds__(256) void cope_mono_kernel(
    const float* __restrict__ q, const float* __restrict__ attn,
    const float* __restrict__ emb, float* __restrict__ out)
{
    const int lane = threadIdx.x & 63;
    const int wave = threadIdx.x >> 6;
    const int r = blockIdx.x * 4 + wave;
    const float qv = q[(size_t)r * DDIM + lane];
    float lv = 0.0f;
    #pragma unroll
    for (int d = 0; d < DDIM; ++d)
        lv = fmaf(__shfl(qv, d), emb[d * NPOSN + lane], lv);
    const float l63 = __shfl(lv, NPOSN - 1);
    const float* __restrict__ arow = attn + (size_t)r * SLEN;
    float* __restrict__ orow = out + (size_t)r * SLEN;
    float carry = 0.0f;
    int jb = SLEN;
    while (jb > 0) {
        jb -= 64;
        const float x = arow[jb + lane];
        float s = sigmoidf_(x);
        #pragma unroll
        for (int off = 1; off < 64; off <<= 1) {
            const float t = __shfl_down(s, off);
            if (lane + off < 64) s += t;
        }
        const float pos = fminf(carry + s, 63.0f);
        const float pf = floorf(pos), w = pos - pf;
        const float lf = __shfl(lv, (int)pf);
        const float lc = __shfl(lv, (int)ceilf(pos));
        orow[jb + lane] = lc * w + lf * (1.0f - w);
        carry += __shfl(s, 0);
        if (carry >= 63.0f) break;
    }
    const float4 v4 = make_float4(l63, l63, l63, l63);
    for (int j = lane * 4; j < jb; j += 256)
        *reinterpret_cast<float4*>(orow + j) = v4;
}

extern "C" void kernel_launch(void* const* d_in, const int* in_sizes, int n_in,
                              void* d_out, int out_size, void* d_ws, size_t ws_size,
                              hipStream_t stream) {
    const float* q    = (const float*)d_in[0];
    const float* attn = (const float*)d_in[1];
    const float* emb  = (const float*)d_in[2];
    float* out = (float*)d_out;

    const size_t ws_need = (size_t)ROWS * NPOSN * sizeof(float);   // 16 MB
    dim3 block(256);
    if (ws_size >= ws_need && d_ws != nullptr) {
        float* table = (float*)d_ws;
        cope_table_kernel<<<dim3(ROWS / 256), block, 0, stream>>>(q, emb, table);
        cope_main_kernel<<<dim3(ROWS / (4 * RPW)), block, 0, stream>>>(attn, table, out);
    } else {
        cope_mono_kernel<<<dim3(ROWS / 4), block, 0, stream>>>(q, attn, emb, out);
    }
}

// Round 6
// 105.420 us; speedup vs baseline: 1.8661x; 1.6247x over previous
//
#include <hip/hip_runtime.h>

// CoPE: gated reverse-cumsum positions + interpolated positional logits.
// B=2,H=16,S=2048,D=64,NPOS=64 -> 65536 rows of length 2048.
//
// R4 lesson: three different schedules (1-row waves / split kernels /
// 4-row batched waves) all land at 164-172 us -> the limit is per-byte,
// not scheduling. Fill kernel evidence: pure writes run 6.58 TB/s with
// FETCH~0. Our ~165 us matches 537MB(write-allocate fetch)+537MB(writeback)
// +70MB(reads) at 6.58 TB/s almost exactly. Hypothesis: normal stores
// read-allocate output lines; nontemporal stores stream them.
//
// R6 = R1 monolithic with all output stores nontemporal. (R5 failed to
// compile: the builtin rejects HIP's float4 class -> use a clang
// ext_vector_type(4) native vector instead.)

#define SLEN 2048
#define DDIM 64
#define NPOSN 64
#define ROWS (2 * 16 * 2048)

typedef float vfloat4 __attribute__((ext_vector_type(4)));

__global__ __launch_bounds__(256) void cope_kernel(
    const float* __restrict__ q,     // [65536, 64]
    const float* __restrict__ attn,  // [65536, 2048]
    const float* __restrict__ emb,   // [64, 64]
    float* __restrict__ out)         // [65536, 2048]
{
    const int lane = threadIdx.x & 63;
    const int wave = threadIdx.x >> 6;
    const int r = blockIdx.x * 4 + wave;

    // logits_int[lane] = sum_d q[r][d] * emb[d][lane]
    const float qv = q[(size_t)r * DDIM + lane];
    float lv = 0.0f;
    #pragma unroll
    for (int d = 0; d < DDIM; ++d)
        lv = fmaf(__shfl(qv, d), emb[d * NPOSN + lane], lv);
    const float l63 = __shfl(lv, NPOSN - 1);

    const float* __restrict__ arow = attn + (size_t)r * SLEN;
    float* __restrict__ orow = out + (size_t)r * SLEN;

    // backward chunked scan with early exit
    float carry = 0.0f;
    int jb = SLEN;
    while (jb > 0) {
        jb -= 64;
        const float x = arow[jb + lane];
        const float g = 1.0f / (1.0f + __expf(-x));   // sigmoid
        float s = g;                                   // reverse incl. scan
        #pragma unroll
        for (int off = 1; off < 64; off <<= 1) {
            const float t = __shfl_down(s, off);
            if (lane + off < 64) s += t;
        }
        const float pos = fminf(carry + s, 63.0f);
        const float pf  = floorf(pos);
        const float w   = pos - pf;
        const float lf  = __shfl(lv, (int)pf);
        const float lc  = __shfl(lv, (int)ceilf(pos));
        __builtin_nontemporal_store(lc * w + lf * (1.0f - w), orow + jb + lane);
        carry += __shfl(s, 0);
        if (carry >= 63.0f) break;
    }

    // fill [0, jb) with logits_int[63] (pos clamps -> w == 0)
    const vfloat4 v4 = { l63, l63, l63, l63 };
    for (int j = lane * 4; j < jb; j += 256)
        __builtin_nontemporal_store(v4, reinterpret_cast<vfloat4*>(orow + j));
}

extern "C" void kernel_launch(void* const* d_in, const int* in_sizes, int n_in,
                              void* d_out, int out_size, void* d_ws, size_t ws_size,
                              hipStream_t stream) {
    const float* q    = (const float*)d_in[0];
    const float* attn = (const float*)d_in[1];
    const float* emb  = (const float*)d_in[2];
    float* out = (float*)d_out;

    dim3 grid(ROWS / 4), block(256);
    cope_kernel<<<grid, block, 0, stream>>>(q, attn, emb, out);
}